// Round 11
// baseline (614.917 us; speedup 1.0000x reference)
//
#include <hip/hip_runtime.h>
#include <hip/hip_cooperative_groups.h>

namespace cg = cooperative_groups;

// Problem constants
constexpr int   kAtoms  = 5000;
constexpr int   kPairs  = 160000;
constexpr int   KD      = 128;   // K
constexpr int   NB      = 8;     // N_BASIS
constexpr int   RH      = 32;    // RAD_HIDDEN
constexpr float kCutoff = 5.0f;
constexpr float kPi     = 3.14159265358979323846f;
constexpr float C1 = 0.2f * 0.1767767f;   // INIT_SCALE * MSG_SCALE
constexpr float C2 = 1.2f * 0.1767767f;   // (1+INIT_SCALE) * MSG_SCALE
constexpr int   TPB    = 512;             // 8 waves/block
constexpr int   BLOCKS = 256;             // 1 block/CU -> coop-safe at any VGPR

__device__ __forceinline__ float silu(float x) { return x / (1.0f + __expf(-x)); }
__device__ __forceinline__ void wave_fence() { __builtin_amdgcn_wave_barrier(); }

// Only the l=0 channel reaches the output; l>=1 / sph / U2 are dead code.
//   F0[a][k] = C1 * sum_p R0_p[k]*e_spec[k];  G0 = F0+F0^2*mix
//   D[a][k]  = sum_p Re0_p[k]*G0[nbr_p][k];   n = G0+C2*D;  V = n+n^2*emix
//   out = head MLP(V)
// Single cooperative kernel (R8 retry — WITHOUT the launch-bounds VGPR cap
// that caused R8's spills): zero -> hist -> scan -> build -> f0 -> d0 -> head.
struct Params {
    const float *pos, *cells;
    const int   *species, *shifts, *ctr, *nbr, *spair;
    const float *embed, *rw1, *rb1, *rw2, *rb2, *ew1, *eb1, *ew2, *eb2;
    const float *mix, *emix, *hw1, *hb1, *hw2, *hb2, *lw, *lb;
    float *rbf, *h2buf, *G0, *V;
    int   *cnt, *off, *cur, *nbrs, *specs, *wk;
    float *out;
};

__global__ __launch_bounds__(TPB) void fused(Params P)
{
    cg::grid_group grid = cg::this_grid();
    const int t    = threadIdx.x;
    const int gsz  = gridDim.x * TPB;
    const int gid  = blockIdx.x * TPB + t;
    const int w    = t >> 6, lane = t & 63;

    __shared__ union SM {
        int part[TPB];                                    // scan
        struct {                                          // f0 phase
            float w1[NB][RH]; float b1v[RH];
            float rb[8][32][NB]; int sp[8][32];
            float H[8][4][RH];
        } f0;
        struct { float h[8][32][RH]; int nbr[8][32]; } d0; // 33 KB max
        struct { float v[8][KD]; float m[8][KD]; } hd;     // head
    } sm;

    // ---- P0: zero ----------------------------------------------------------
    for (int i = gid; i < kAtoms; i += gsz) P.cnt[i] = 0;
    if (gid < 8) P.wk[gid] = 0;
    grid.sync();

    // ---- P1: histogram (grid-wide atomics, parallel) -----------------------
    for (int p = gid; p < kPairs; p += gsz) atomicAdd(&P.cnt[P.ctr[p]], 1);
    grid.sync();

    // ---- P2: exclusive scan (block 0) --------------------------------------
    if (blockIdx.x == 0) {
        const int CH = 10;                    // 512*10 = 5120 >= 5000
        int base = t * CH, loc[CH], run = 0;
        #pragma unroll
        for (int i = 0; i < CH; i++) {
            int idx = base + i;
            int v = (idx < kAtoms) ? P.cnt[idx] : 0;
            loc[i] = run; run += v;
        }
        sm.part[t] = run; __syncthreads();
        for (int st = 1; st < TPB; st <<= 1) {
            int v = (t >= st) ? sm.part[t - st] : 0;
            __syncthreads(); sm.part[t] += v; __syncthreads();
        }
        int excl = t ? sm.part[t - 1] : 0;
        #pragma unroll
        for (int i = 0; i < CH; i++) {
            int idx = base + i;
            if (idx < kAtoms) { P.off[idx] = excl + loc[i]; P.cur[idx] = excl + loc[i]; }
        }
        if (t == TPB - 1) P.off[kAtoms] = sm.part[TPB - 1];
    }
    grid.sync();

    // ---- P3: build rbf + erad-hidden h2, CSR slot order --------------------
    for (int p = gid; p < kPairs; p += gsz) {
        int ci = P.ctr[p], ni = P.nbr[p], sp = P.spair[p];
        float s0 = (float)P.shifts[p*3+0] - 1.0f;
        float s1 = (float)P.shifts[p*3+1] - 1.0f;
        float s2 = (float)P.shifts[p*3+2] - 1.0f;
        const float* C = P.cells + sp * 9;
        float vx = P.pos[ni*3+0]-P.pos[ci*3+0]+s0*C[0]+s1*C[3]+s2*C[6];
        float vy = P.pos[ni*3+1]-P.pos[ci*3+1]+s0*C[1]+s1*C[4]+s2*C[7];
        float vz = P.pos[ni*3+2]-P.pos[ci*3+2]+s0*C[2]+s1*C[5]+s2*C[8];
        float d = sqrtf(vx*vx + vy*vy + vz*vz + 1e-12f);
        float fcut = (d < kCutoff) ? 0.5f*(__cosf(kPi*d/kCutoff)+1.0f) : 0.0f;
        float r[NB];
        #pragma unroll
        for (int i = 0; i < NB; i++) {
            float tt = d - (kCutoff/(NB-1))*(float)i;
            r[i] = __expf(-2.0f*tt*tt)*fcut;
        }
        int slot = atomicAdd(&P.cur[ci], 1);
        P.nbrs[slot]  = ni;
        P.specs[slot] = P.species[ni];
        float4* rdst = (float4*)(P.rbf + (size_t)slot*NB);
        rdst[0] = make_float4(r[0],r[1],r[2],r[3]);
        rdst[1] = make_float4(r[4],r[5],r[6],r[7]);
        float* hdst = P.h2buf + (size_t)slot*RH;
        #pragma unroll
        for (int jq = 0; jq < RH/4; jq++) {
            float4 hv; float* pv = (float*)&hv;
            #pragma unroll
            for (int u = 0; u < 4; u++) {
                int j = 4*jq + u;
                float acc = P.eb1[j];
                #pragma unroll
                for (int i = 0; i < NB; i++) acc += r[i]*P.ew1[i*RH+j];
                pv[u] = silu(acc);
            }
            *(float4*)(hdst + 4*jq) = hv;
        }
    }
    grid.sync();

    // ---- P4: f0 -> G0 (species-factored, LDS-staged rbf, wave = atom) ------
    {
        for (int idx = t; idx < NB*RH; idx += TPB)
            sm.f0.w1[idx >> 5][idx & 31] = P.rw1[idx];
        if (t < RH) sm.f0.b1v[t] = P.rb1[t];
        __syncthreads();

        int g = lane >> 5, j = lane & 31;
        float b1j = sm.f0.b1v[j];
        for (;;) {
            int a; if (lane == 0) a = atomicAdd(&P.wk[0], 1);
            a = __shfl(a, 0);
            if (a >= kAtoms) break;
            int start = P.off[a], end = P.off[a+1];
            float H0=0,H1=0,H2=0,H3=0; int n0=0,n1=0,n2=0,n3=0;
            for (int c = start; c < end; c += 32) {
                int mm = min(32, end - c);
                float4 rv = *((const float4*)(P.rbf + (size_t)c*NB) + lane);
                ((float4*)sm.f0.rb[w])[lane] = rv;
                if (lane < mm) sm.f0.sp[w][lane] = P.specs[c + lane];
                wave_fence();
                for (int pr = g; pr < mm; pr += 2) {
                    const float* rb = sm.f0.rb[w][pr];
                    float acc = b1j;
                    #pragma unroll
                    for (int i = 0; i < NB; i++) acc += rb[i]*sm.f0.w1[i][j];
                    float h = silu(acc);
                    int s = sm.f0.sp[w][pr];
                    H0 += (s==0)?h:0.0f; H1 += (s==1)?h:0.0f;
                    H2 += (s==2)?h:0.0f; H3 += (s==3)?h:0.0f;
                    n0 += (s==0); n1 += (s==1); n2 += (s==2); n3 += (s==3);
                }
                wave_fence();
            }
            H0 += __shfl_xor(H0,32); H1 += __shfl_xor(H1,32);
            H2 += __shfl_xor(H2,32); H3 += __shfl_xor(H3,32);
            n0 += __shfl_xor(n0,32); n1 += __shfl_xor(n1,32);
            n2 += __shfl_xor(n2,32); n3 += __shfl_xor(n3,32);
            if (lane < 32) {
                sm.f0.H[w][0][j]=H0; sm.f0.H[w][1][j]=H1;
                sm.f0.H[w][2][j]=H2; sm.f0.H[w][3][j]=H3;
            }
            wave_fence();
            float fn0=(float)n0, fn1=(float)n1, fn2=(float)n2, fn3=(float)n3;
            #pragma unroll
            for (int half = 0; half < 2; half++) {
                int k = lane + 64*half;
                float e0=P.embed[0*KD+k], e1=P.embed[1*KD+k];
                float e2=P.embed[2*KD+k], e3=P.embed[3*KD+k];
                float Q0=0,Q1=0,Q2=0,Q3=0;
                #pragma unroll
                for (int jq = 0; jq < RH/4; jq++) {
                    float4 h0=*(const float4*)&sm.f0.H[w][0][4*jq];
                    float4 h1=*(const float4*)&sm.f0.H[w][1][4*jq];
                    float4 h2=*(const float4*)&sm.f0.H[w][2][4*jq];
                    float4 h3=*(const float4*)&sm.f0.H[w][3][4*jq];
                    float wa=P.rw2[(4*jq+0)*(3*KD)+k], wbv=P.rw2[(4*jq+1)*(3*KD)+k];
                    float wc=P.rw2[(4*jq+2)*(3*KD)+k], wd=P.rw2[(4*jq+3)*(3*KD)+k];
                    Q0 += h0.x*wa+h0.y*wbv+h0.z*wc+h0.w*wd;
                    Q1 += h1.x*wa+h1.y*wbv+h1.z*wc+h1.w*wd;
                    Q2 += h2.x*wa+h2.y*wbv+h2.z*wc+h2.w*wd;
                    Q3 += h3.x*wa+h3.y*wbv+h3.z*wc+h3.w*wd;
                }
                float F = P.rb2[k]*(fn0*e0+fn1*e1+fn2*e2+fn3*e3)
                        + e0*Q0 + e1*Q1 + e2*Q2 + e3*Q3;
                float F0v = C1*F;
                P.G0[(size_t)a*KD+k] = F0v + F0v*F0v*P.mix[k];
            }
            wave_fence();
        }
    }
    grid.sync();

    // ---- P5: d0 -> V (LDS-staged h2 chunks, wave = atom) -------------------
    {
        int k0 = 2*lane, k1 = 2*lane + 1;
        float w2c0[RH], w2c1[RH];
        #pragma unroll
        for (int j = 0; j < RH; j++) {
            float2 wv = *(const float2*)&P.ew2[j*(3*KD)+k0];
            w2c0[j] = wv.x; w2c1[j] = wv.y;
        }
        float b2k0 = P.eb2[k0], b2k1 = P.eb2[k1];
        float ex0  = P.emix[k0], ex1 = P.emix[k1];
        for (;;) {
            int a; if (lane == 0) a = atomicAdd(&P.wk[1], 1);
            a = __shfl(a, 0);
            if (a >= kAtoms) break;
            int start = P.off[a], end = P.off[a+1];
            float D0 = 0.0f, D1 = 0.0f;
            for (int c = start; c < end; c += 32) {
                int mm = min(32, end - c);
                const float4* src = (const float4*)(P.h2buf + (size_t)c*RH);
                #pragma unroll
                for (int q = 0; q < 4; q++)
                    ((float4*)sm.d0.h[w])[q*64 + lane] = src[q*64 + lane];
                if (lane < mm) sm.d0.nbr[w][lane] = P.nbrs[c + lane];
                wave_fence();
                #pragma unroll 2
                for (int i = 0; i < mm; i++) {
                    int nb = sm.d0.nbr[w][i];
                    float2 gv = *(const float2*)(P.G0 + (size_t)nb*KD + k0);
                    float R0 = b2k0, R1 = b2k1;
                    #pragma unroll
                    for (int q = 0; q < RH/4; q++) {
                        float4 h4 = *(const float4*)&sm.d0.h[w][i][4*q];
                        R0 += h4.x*w2c0[4*q+0] + h4.y*w2c0[4*q+1]
                            + h4.z*w2c0[4*q+2] + h4.w*w2c0[4*q+3];
                        R1 += h4.x*w2c1[4*q+0] + h4.y*w2c1[4*q+1]
                            + h4.z*w2c1[4*q+2] + h4.w*w2c1[4*q+3];
                    }
                    D0 += R0*gv.x; D1 += R1*gv.y;
                }
                wave_fence();
            }
            float2 ga = *(const float2*)(P.G0 + (size_t)a*KD + k0);
            float q0 = ga.x + C2*D0, q1 = ga.y + C2*D1;
            float2 vo; vo.x = q0 + q0*q0*ex0; vo.y = q1 + q1*q1*ex1;
            *(float2*)(P.V + (size_t)a*KD + k0) = vo;
        }
    }
    grid.sync();

    // ---- P6: head MLP (8 atoms/tile, 4 groups x 128 j) ---------------------
    {
        int j = t & 127, grp = t >> 7;       // grp 0..3
        int a0 = grp*2, a1 = grp*2 + 1;
        float lb0 = P.lb[0];
        for (int tile = blockIdx.x; tile < kAtoms/8; tile += gridDim.x) {
            int abase = tile*8;
            __syncthreads();
            sm.hd.v[a0][j] = P.V[(size_t)(abase+a0)*KD + j];
            sm.hd.v[a1][j] = P.V[(size_t)(abase+a1)*KD + j];
            __syncthreads();
            float acc0 = P.hb1[j], acc1 = acc0;
            for (int kk = 0; kk < KD; kk += 4) {
                float wa=P.hw1[(kk+0)*KD+j], wbv=P.hw1[(kk+1)*KD+j];
                float wc=P.hw1[(kk+2)*KD+j], wd=P.hw1[(kk+3)*KD+j];
                float4 v0 = *(const float4*)&sm.hd.v[a0][kk];
                float4 v1 = *(const float4*)&sm.hd.v[a1][kk];
                acc0 += v0.x*wa + v0.y*wbv + v0.z*wc + v0.w*wd;
                acc1 += v1.x*wa + v1.y*wbv + v1.z*wc + v1.w*wd;
            }
            sm.hd.m[a0][j] = silu(acc0);
            sm.hd.m[a1][j] = silu(acc1);
            __syncthreads();
            acc0 = P.hb2[j]; acc1 = acc0;
            for (int kk = 0; kk < KD; kk += 4) {
                float wa=P.hw2[(kk+0)*KD+j], wbv=P.hw2[(kk+1)*KD+j];
                float wc=P.hw2[(kk+2)*KD+j], wd=P.hw2[(kk+3)*KD+j];
                float4 v0 = *(const float4*)&sm.hd.m[a0][kk];
                float4 v1 = *(const float4*)&sm.hd.m[a1][kk];
                acc0 += v0.x*wa + v0.y*wbv + v0.z*wc + v0.w*wd;
                acc1 += v1.x*wa + v1.y*wbv + v1.z*wc + v1.w*wd;
            }
            float lwj = P.lw[j];
            __syncthreads();
            sm.hd.v[a0][j] = silu(acc0)*lwj;
            sm.hd.v[a1][j] = silu(acc1)*lwj;
            __syncthreads();
            for (int s = 64; s > 0; s >>= 1) {
                if (j < s) {
                    sm.hd.v[a0][j] += sm.hd.v[a0][j+s];
                    sm.hd.v[a1][j] += sm.hd.v[a1][j+s];
                }
                __syncthreads();
            }
            if (t < 8) P.out[abase + t] = sm.hd.v[t][0] + lb0;
        }
    }
}

// ---------------------------------------------------------------------------
extern "C" void kernel_launch(void* const* d_in, const int* in_sizes, int n_in,
                              void* d_out, int out_size, void* d_ws, size_t ws_size,
                              hipStream_t stream) {
    Params P;
    P.pos     = (const float*)d_in[0];
    P.cells   = (const float*)d_in[1];
    P.species = (const int*)d_in[2];
    P.shifts  = (const int*)d_in[3];
    P.ctr     = (const int*)d_in[4];
    P.nbr     = (const int*)d_in[5];
    P.spair   = (const int*)d_in[6];
    P.embed   = (const float*)d_in[7];
    P.rw1     = (const float*)d_in[8];
    P.rb1     = (const float*)d_in[9];
    P.rw2     = (const float*)d_in[10];
    P.rb2     = (const float*)d_in[11];
    P.ew1     = (const float*)d_in[12];
    P.eb1     = (const float*)d_in[13];
    P.ew2     = (const float*)d_in[14];
    P.eb2     = (const float*)d_in[15];
    P.mix     = (const float*)d_in[16];
    P.emix    = (const float*)d_in[17];
    P.hw1     = (const float*)d_in[18];
    P.hb1     = (const float*)d_in[19];
    P.hw2     = (const float*)d_in[20];
    P.hb2     = (const float*)d_in[21];
    P.lw      = (const float*)d_in[22];
    P.lb      = (const float*)d_in[23];
    // U2 (d_in[24]) unused: l>=1 channels are dead code for the output.

    float* f = (float*)d_ws;
    P.rbf   = f;                                 // 160000*8  = 5.12 MB
    P.h2buf = P.rbf + (size_t)kPairs*NB;         // 160000*32 = 20.48 MB
    P.G0    = P.h2buf + (size_t)kPairs*RH;       // 5000*128
    P.V     = P.G0 + (size_t)kAtoms*KD;          // 5000*128
    int* ip = (int*)(P.V + (size_t)kAtoms*KD);
    P.cnt   = ip;            ip += kAtoms;
    P.off   = ip;            ip += kAtoms + 1;
    P.cur   = ip;            ip += kAtoms;
    P.nbrs  = ip;            ip += kPairs;
    P.specs = ip;            ip += kPairs;
    P.wk    = ip;
    P.out   = (float*)d_out;

    void* kargs[] = { &P };
    hipError_t e = hipLaunchCooperativeKernel((const void*)fused,
                                              dim3(BLOCKS), dim3(TPB),
                                              kargs, 0, stream);
    if (e != hipSuccess) {
        hipLaunchCooperativeKernel((const void*)fused,
                                   dim3(128), dim3(TPB), kargs, 0, stream);
    }
}